// Round 2
// baseline (361.243 us; speedup 1.0000x reference)
//
#include <hip/hip_runtime.h>

#define HEADS  16
#define DH     64
#define SEQ    2048
#define NBATCH 2
#define EMB    1024
#define MTOT   (NBATCH * SEQ)  // 4096

typedef short  s16x8 __attribute__((ext_vector_type(8)));
typedef float  f32x4 __attribute__((ext_vector_type(4)));
typedef unsigned short u16;
typedef unsigned short u16x4 __attribute__((ext_vector_type(4)));

__device__ __forceinline__ u16 f2bf(float f) {
  unsigned u = __builtin_bit_cast(unsigned, f);
  u += 0x7fffu + ((u >> 16) & 1u);   // RNE
  return (u16)(u >> 16);
}

// ---------------- fp32 -> bf16 bulk convert (x) ----------------
__global__ void cvt_x_kernel(const float* __restrict__ x, u16* __restrict__ xb) {
  int i = (blockIdx.x * 256 + threadIdx.x) * 4;
  float4 v = *(const float4*)(x + i);
  u16x4 o;
  o.x = f2bf(v.x); o.y = f2bf(v.y); o.z = f2bf(v.z); o.w = f2bf(v.w);
  *(u16x4*)(xb + i) = o;
}

// ---------------- weight transpose + convert: Wt[n][k] = bf16(W[k][n]) ----------------
__global__ void cvt_wt_kernel(const float* __restrict__ Wq, const float* __restrict__ Wk,
                              const float* __restrict__ Wv, const float* __restrict__ Wo,
                              u16* __restrict__ Wqt, u16* __restrict__ Wkt,
                              u16* __restrict__ Wvt, u16* __restrict__ Wot) {
  __shared__ float tile[32][33];
  const float* W; u16* T;
  switch (blockIdx.z) {
    case 0:  W = Wq; T = Wqt; break;
    case 1:  W = Wk; T = Wkt; break;
    case 2:  W = Wv; T = Wvt; break;
    default: W = Wo; T = Wot; break;
  }
  int n0 = blockIdx.x * 32, k0 = blockIdx.y * 32;
  int tx = threadIdx.x, ty = threadIdx.y;
#pragma unroll
  for (int r = 0; r < 32; r += 8)
    tile[ty + r][tx] = W[(size_t)(k0 + ty + r) * EMB + n0 + tx];
  __syncthreads();
#pragma unroll
  for (int r = 0; r < 32; r += 8)
    T[(size_t)(n0 + ty + r) * EMB + k0 + tx] = f2bf(tile[tx][ty + r]);
}

// ---------------- GEMM: C(M,N) = A(M,K) @ Bt(N,K)^T + bias ----------------
// MODE 0: fp32 out[m*N + n]
// MODE 1: bf16 out[((b*H+h)*S + s)*64 + d]      (m = b*S+s, n = h*64+d)
// MODE 2: bf16 out[((b*H+h)*64 + d)*S + s]      (V transposed for attention)
template <int MODE>
__global__ __launch_bounds__(256) void gemm_bt(const u16* __restrict__ A,
                                               const u16* __restrict__ Bt,
                                               const float* __restrict__ bias,
                                               void* __restrict__ outp,
                                               int Mdim, int Ndim, int Kdim) {
  __shared__ __align__(16) u16 As[128 * 64];
  __shared__ __align__(16) u16 Bs[128 * 64];
  const int tid  = threadIdx.x;
  const int lane = tid & 63, w = tid >> 6;
  const int wm = w >> 1, wn = w & 1;
  const int lr = lane & 15, lq = lane >> 4;
  const int m0 = blockIdx.y * 128, n0 = blockIdx.x * 128;
  f32x4 acc[4][4];
#pragma unroll
  for (int i = 0; i < 4; i++)
#pragma unroll
    for (int j = 0; j < 4; j++)
      acc[i][j] = (f32x4){0.f, 0.f, 0.f, 0.f};

  for (int k0 = 0; k0 < Kdim; k0 += 64) {
    __syncthreads();
    // stage 128x64 tiles: 1024 chunks of 8 u16 -> 4 iterations of 256 threads
#pragma unroll
    for (int j = 0; j < 4; j++) {
      int c = tid + 256 * j;
      int row = c >> 3, c8 = c & 7;
      *(s16x8*)&As[row * 64 + c8 * 8] =
          *(const s16x8*)&A[(size_t)(m0 + row) * Kdim + k0 + c8 * 8];
      *(s16x8*)&Bs[row * 64 + c8 * 8] =
          *(const s16x8*)&Bt[(size_t)(n0 + row) * Kdim + k0 + c8 * 8];
    }
    __syncthreads();
#pragma unroll
    for (int kk = 0; kk < 64; kk += 32) {
      s16x8 af[4], bf[4];
#pragma unroll
      for (int i = 0; i < 4; i++)
        af[i] = *(const s16x8*)&As[(wm * 64 + i * 16 + lr) * 64 + kk + lq * 8];
#pragma unroll
      for (int i = 0; i < 4; i++)
        bf[i] = *(const s16x8*)&Bs[(wn * 64 + i * 16 + lr) * 64 + kk + lq * 8];
#pragma unroll
      for (int i = 0; i < 4; i++)
#pragma unroll
        for (int j = 0; j < 4; j++)
          acc[i][j] = __builtin_amdgcn_mfma_f32_16x16x32_bf16(af[i], bf[j], acc[i][j], 0, 0, 0);
    }
  }
#pragma unroll
  for (int i = 0; i < 4; i++) {
#pragma unroll
    for (int j = 0; j < 4; j++) {
      int col   = n0 + wn * 64 + j * 16 + lr;
      int mbase = m0 + wm * 64 + i * 16 + lq * 4;
      float bv  = bias[col];
      if (MODE == 0) {
        float* out = (float*)outp;
#pragma unroll
        for (int r = 0; r < 4; r++)
          out[(size_t)(mbase + r) * Ndim + col] = acc[i][j][r] + bv;
      } else if (MODE == 1) {
        u16* out = (u16*)outp;
        int h = col >> 6, d = col & 63;
#pragma unroll
        for (int r = 0; r < 4; r++) {
          int m = mbase + r, b = m >> 11, s = m & (SEQ - 1);
          out[((size_t)(b * HEADS + h) * SEQ + s) * DH + d] = f2bf(acc[i][j][r] + bv);
        }
      } else {
        u16* out = (u16*)outp;
        int h = col >> 6, d = col & 63;
        int b = mbase >> 11, s = mbase & (SEQ - 1);
        u16x4 pk;
        pk.x = f2bf(acc[i][j][0] + bv);
        pk.y = f2bf(acc[i][j][1] + bv);
        pk.z = f2bf(acc[i][j][2] + bv);
        pk.w = f2bf(acc[i][j][3] + bv);
        *(u16x4*)&out[((size_t)(b * HEADS + h) * DH + d) * SEQ + s] = pk;
      }
    }
  }
}

// ---------------- fused causal attention (flash-style) ----------------
// grid: (SEQ/64, NBATCH*HEADS); 256 threads = 4 waves, wave w owns q-rows [w*16, w*16+16)
__global__ __launch_bounds__(256) void attn_fwd(const u16* __restrict__ Q,
                                                const u16* __restrict__ Kg,
                                                const u16* __restrict__ Vt,
                                                u16* __restrict__ O) {
  __shared__ __align__(16) u16 Ks[64 * 80];      // [key][d], stride 80 (160B, 16B-aligned)
  __shared__ __align__(16) u16 Vs[64 * 80];      // [d][key]
  __shared__ __align__(16) u16 Ps[4][16 * 80];   // per-wave P tile [qrow][key]
  const int tid = threadIdx.x, lane = tid & 63, w = tid >> 6;
  const int lr = lane & 15, lq = lane >> 4;
  const int bh = blockIdx.y;
  const int qt = blockIdx.x, q0 = qt * 64;
  const size_t qkbase = (size_t)bh * SEQ * DH;
  const size_t vbase  = (size_t)bh * DH * SEQ;

  // Q fragments for this wave's 16 rows (A-operand layout), kept in registers
  s16x8 qf[2];
  {
    const u16* qrow = Q + qkbase + (size_t)(q0 + w * 16 + lr) * DH;
    qf[0] = *(const s16x8*)&qrow[lq * 8];
    qf[1] = *(const s16x8*)&qrow[32 + lq * 8];
  }
  f32x4 o[4];
#pragma unroll
  for (int t = 0; t < 4; t++) o[t] = (f32x4){0.f, 0.f, 0.f, 0.f};
  float mrow[4] = {-3e38f, -3e38f, -3e38f, -3e38f};
  float lsum[4] = {0.f, 0.f, 0.f, 0.f};

  const int nkt = qt + 1;
  for (int kt = 0; kt < nkt; ++kt) {
    __syncthreads();  // protect LDS from previous iteration's readers
#pragma unroll
    for (int j = 0; j < 2; j++) {
      int c = tid + 256 * j;
      int row = c >> 3, c8 = c & 7;
      *(s16x8*)&Ks[row * 80 + c8 * 8] =
          *(const s16x8*)&Kg[qkbase + (size_t)(kt * 64 + row) * DH + c8 * 8];
      *(s16x8*)&Vs[row * 80 + c8 * 8] =
          *(const s16x8*)&Vt[vbase + (size_t)row * SEQ + kt * 64 + c8 * 8];
    }
    __syncthreads();

    // S = Q @ K^T  (16 x 64 per wave)
    f32x4 sc[4];
#pragma unroll
    for (int t = 0; t < 4; t++) {
      s16x8 kf0 = *(const s16x8*)&Ks[(t * 16 + lr) * 80 + lq * 8];
      s16x8 kf1 = *(const s16x8*)&Ks[(t * 16 + lr) * 80 + 32 + lq * 8];
      f32x4 z = (f32x4){0.f, 0.f, 0.f, 0.f};
      z = __builtin_amdgcn_mfma_f32_16x16x32_bf16(qf[0], kf0, z, 0, 0, 0);
      z = __builtin_amdgcn_mfma_f32_16x16x32_bf16(qf[1], kf1, z, 0, 0, 0);
      sc[t] = z;
    }

    // online softmax (row = w*16 + lq*4 + r local; col = kt*64 + t*16 + lr)
    const bool diag = (kt == qt);
    float pv[4][4], rmax[4], rsum[4], alpha[4];
#pragma unroll
    for (int r = 0; r < 4; r++) {
      int qrow = w * 16 + lq * 4 + r;
      float mx = -3e38f;
#pragma unroll
      for (int t = 0; t < 4; t++) {
        float s = sc[t][r] * 0.03125f;  // 1/sqrt(1024)
        if (diag && (t * 16 + lr) > qrow) s = -1e9f;
        pv[t][r] = s;
        mx = fmaxf(mx, s);
      }
      rmax[r] = mx;
    }
#pragma unroll
    for (int off = 1; off < 16; off <<= 1)
#pragma unroll
      for (int r = 0; r < 4; r++) rmax[r] = fmaxf(rmax[r], __shfl_xor(rmax[r], off));
#pragma unroll
    for (int r = 0; r < 4; r++) {
      float mnew = fmaxf(mrow[r], rmax[r]);
      alpha[r] = __expf(mrow[r] - mnew);
      mrow[r] = mnew;
      float sum = 0.f;
#pragma unroll
      for (int t = 0; t < 4; t++) {
        float p = __expf(pv[t][r] - mnew);
        pv[t][r] = p;
        sum += p;
      }
      rsum[r] = sum;
    }
#pragma unroll
    for (int off = 1; off < 16; off <<= 1)
#pragma unroll
      for (int r = 0; r < 4; r++) rsum[r] += __shfl_xor(rsum[r], off);
#pragma unroll
    for (int r = 0; r < 4; r++) {
      lsum[r] = lsum[r] * alpha[r] + rsum[r];
#pragma unroll
      for (int t = 0; t < 4; t++) o[t][r] *= alpha[r];
    }

    // P -> LDS (bf16), then back as A-operand
    u16* pw = &Ps[w][0];
#pragma unroll
    for (int t = 0; t < 4; t++)
#pragma unroll
      for (int r = 0; r < 4; r++)
        pw[(lq * 4 + r) * 80 + t * 16 + lr] = f2bf(pv[t][r]);
    __syncthreads();

    // O += P @ V
#pragma unroll
    for (int kc = 0; kc < 2; kc++) {
      s16x8 pf = *(const s16x8*)&pw[lr * 80 + kc * 32 + lq * 8];
#pragma unroll
      for (int t = 0; t < 4; t++) {
        s16x8 vf = *(const s16x8*)&Vs[(t * 16 + lr) * 80 + kc * 32 + lq * 8];
        o[t] = __builtin_amdgcn_mfma_f32_16x16x32_bf16(pf, vf, o[t], 0, 0, 0);
      }
    }
  }

  // epilogue: O[m][h*64+d] bf16, m = b*SEQ + q0 + w*16 + lq*4 + r
  const int b = bh >> 4, h = bh & 15;
#pragma unroll
  for (int t = 0; t < 4; t++) {
#pragma unroll
    for (int r = 0; r < 4; r++) {
      int m = b * SEQ + q0 + w * 16 + lq * 4 + r;
      O[(size_t)m * EMB + h * 64 + t * 16 + lr] = f2bf(o[t][r] / lsum[r]);
    }
  }
}

extern "C" void kernel_launch(void* const* d_in, const int* in_sizes, int n_in,
                              void* d_out, int out_size, void* d_ws, size_t ws_size,
                              hipStream_t stream) {
  const float* x  = (const float*)d_in[0];
  // d_in[1] = mask scalar (always 1 -> causal)
  const float* Wq = (const float*)d_in[2];
  const float* bq = (const float*)d_in[3];
  const float* Wk = (const float*)d_in[4];
  const float* bk = (const float*)d_in[5];
  const float* Wv = (const float*)d_in[6];
  const float* bv = (const float*)d_in[7];
  const float* Wo = (const float*)d_in[8];
  const float* bo = (const float*)d_in[9];

  char* ws = (char*)d_ws;
  const size_t MB = 1024 * 1024;
  u16* Qb  = (u16*)(ws + 0 * MB);    // [B][H][S][Dh] bf16, 8 MB
  u16* Kb  = (u16*)(ws + 8 * MB);    // [B][H][S][Dh] bf16, 8 MB
  u16* Vtb = (u16*)(ws + 16 * MB);   // [B][H][Dh][S] bf16, 8 MB
  u16* xb  = (u16*)(ws + 24 * MB);   // [M][E] bf16, 8 MB
  u16* Ob  = xb;                     // alias: xb dead after QKV GEMMs
  u16* Wqt = (u16*)(ws + 32 * MB);
  u16* Wkt = (u16*)(ws + 34 * MB);
  u16* Wvt = (u16*)(ws + 36 * MB);
  u16* Wot = (u16*)(ws + 38 * MB);

  cvt_x_kernel<<<(MTOT * EMB) / (256 * 4), 256, 0, stream>>>(x, xb);
  cvt_wt_kernel<<<dim3(EMB / 32, EMB / 32, 4), dim3(32, 8), 0, stream>>>(
      Wq, Wk, Wv, Wo, Wqt, Wkt, Wvt, Wot);

  dim3 ggrid(EMB / 128, MTOT / 128);
  gemm_bt<1><<<ggrid, 256, 0, stream>>>(xb, Wqt, bq, Qb, MTOT, EMB, EMB);
  gemm_bt<1><<<ggrid, 256, 0, stream>>>(xb, Wkt, bk, Kb, MTOT, EMB, EMB);
  gemm_bt<2><<<ggrid, 256, 0, stream>>>(xb, Wvt, bv, Vtb, MTOT, EMB, EMB);

  attn_fwd<<<dim3(SEQ / 64, NBATCH * HEADS), 256, 0, stream>>>(Qb, Kb, Vtb, Ob);

  gemm_bt<0><<<ggrid, 256, 0, stream>>>(Ob, Wot, bo, (float*)d_out, MTOT, EMB, EMB);
}

// Round 3
// 223.320 us; speedup vs baseline: 1.6176x; 1.6176x over previous
//
#include <hip/hip_runtime.h>

#define HEADS  16
#define DH     64
#define SEQ    2048
#define NBATCH 2
#define EMB    1024
#define MTOT   (NBATCH * SEQ)  // 4096

typedef short  s16x8 __attribute__((ext_vector_type(8)));
typedef float  f32x4 __attribute__((ext_vector_type(4)));
typedef unsigned short u16;
typedef unsigned short u16x4 __attribute__((ext_vector_type(4)));

__device__ __forceinline__ u16 f2bf(float f) {
  unsigned u = __builtin_bit_cast(unsigned, f);
  u += 0x7fffu + ((u >> 16) & 1u);   // RNE
  return (u16)(u >> 16);
}

// async global->LDS, 16B per lane; lds ptr must be wave-uniform base (HW adds lane*16)
__device__ __forceinline__ void gll16(const u16* g, u16* l) {
  __builtin_amdgcn_global_load_lds(
      (const __attribute__((address_space(1))) unsigned int*)g,
      (__attribute__((address_space(3))) unsigned int*)l, 16, 0, 0);
}

// ---------------- fp32 -> bf16 bulk convert (x) ----------------
__global__ void cvt_x_kernel(const float* __restrict__ x, u16* __restrict__ xb) {
  int i = (blockIdx.x * 256 + threadIdx.x) * 4;
  float4 v = *(const float4*)(x + i);
  u16x4 o;
  o.x = f2bf(v.x); o.y = f2bf(v.y); o.z = f2bf(v.z); o.w = f2bf(v.w);
  *(u16x4*)(xb + i) = o;
}

// ---------------- weight transpose + convert: Wt[n][k] = bf16(W[k][n]) ----------------
__global__ void cvt_wt_kernel(const float* __restrict__ Wq, const float* __restrict__ Wk,
                              const float* __restrict__ Wv, const float* __restrict__ Wo,
                              u16* __restrict__ Wqt, u16* __restrict__ Wkt,
                              u16* __restrict__ Wvt, u16* __restrict__ Wot) {
  __shared__ float tile[32][33];
  const float* W; u16* T;
  switch (blockIdx.z) {
    case 0:  W = Wq; T = Wqt; break;
    case 1:  W = Wk; T = Wkt; break;
    case 2:  W = Wv; T = Wvt; break;
    default: W = Wo; T = Wot; break;
  }
  int n0 = blockIdx.x * 32, k0 = blockIdx.y * 32;
  int tx = threadIdx.x, ty = threadIdx.y;
#pragma unroll
  for (int r = 0; r < 32; r += 8)
    tile[ty + r][tx] = W[(size_t)(k0 + ty + r) * EMB + n0 + tx];
  __syncthreads();
#pragma unroll
  for (int r = 0; r < 32; r += 8)
    T[(size_t)(n0 + ty + r) * EMB + k0 + tx] = f2bf(tile[tx][ty + r]);
}

// ---------------- GEMM mainloop: BM=128, BN=64, BK=64, 256 thr / 4 waves ----------------
// wave grid 2(m) x 2(n): wave covers 64 rows x 32 cols -> acc[4][2]
// As/Bs row-major [row][64], staged via global_load_lds width 16.
__device__ __forceinline__ void gemm_core(const u16* __restrict__ A, const u16* __restrict__ Bt,
                                          u16* As, u16* Bs, int m0, int n0, f32x4 acc[4][2]) {
  const int tid = threadIdx.x;
  const int lane = tid & 63, w = tid >> 6;
  const int wm = w >> 1, wn = w & 1;
  const int lr = lane & 15, lq = lane >> 4;
#pragma unroll
  for (int i = 0; i < 4; i++)
#pragma unroll
    for (int j = 0; j < 2; j++)
      acc[i][j] = (f32x4){0.f, 0.f, 0.f, 0.f};

  for (int k0 = 0; k0 < EMB; k0 += 64) {
    __syncthreads();
#pragma unroll
    for (int j = 0; j < 4; j++) {
      int c = tid + 256 * j;
      gll16(&A[(size_t)(m0 + (c >> 3)) * EMB + k0 + (c & 7) * 8],
            &As[(w * 64 + 256 * j) * 8]);
    }
#pragma unroll
    for (int j = 0; j < 2; j++) {
      int c = tid + 256 * j;
      gll16(&Bt[(size_t)(n0 + (c >> 3)) * EMB + k0 + (c & 7) * 8],
            &Bs[(w * 64 + 256 * j) * 8]);
    }
    __syncthreads();
#pragma unroll
    for (int kk = 0; kk < 64; kk += 32) {
      s16x8 af[4], bf[2];
#pragma unroll
      for (int i = 0; i < 4; i++)
        af[i] = *(const s16x8*)&As[(wm * 64 + i * 16 + lr) * 64 + kk + lq * 8];
#pragma unroll
      for (int j = 0; j < 2; j++)
        bf[j] = *(const s16x8*)&Bs[(wn * 32 + j * 16 + lr) * 64 + kk + lq * 8];
#pragma unroll
      for (int i = 0; i < 4; i++)
#pragma unroll
        for (int j = 0; j < 2; j++)
          acc[i][j] = __builtin_amdgcn_mfma_f32_16x16x32_bf16(af[i], bf[j], acc[i][j], 0, 0, 0);
    }
  }
}

// QKV fused: blockIdx.z selects {Wq->Qb mode1, Wk->Kb mode1, Wv->Vtb mode2}
__global__ __launch_bounds__(256) void gemm_qkv(const u16* __restrict__ xb,
                                                const u16* __restrict__ Wqt, const u16* __restrict__ Wkt,
                                                const u16* __restrict__ Wvt,
                                                const float* __restrict__ bq, const float* __restrict__ bk,
                                                const float* __restrict__ bv,
                                                u16* __restrict__ Qb, u16* __restrict__ Kb,
                                                u16* __restrict__ Vtb) {
  __shared__ __align__(16) u16 As[128 * 64];
  __shared__ __align__(16) u16 Bs[64 * 64];
  const u16* Bt; const float* bias; u16* out; int mode;
  switch (blockIdx.z) {
    case 0:  Bt = Wqt; bias = bq; out = Qb;  mode = 1; break;
    case 1:  Bt = Wkt; bias = bk; out = Kb;  mode = 1; break;
    default: Bt = Wvt; bias = bv; out = Vtb; mode = 2; break;
  }
  const int m0 = blockIdx.y * 128, n0 = blockIdx.x * 64;
  f32x4 acc[4][2];
  gemm_core(xb, Bt, As, Bs, m0, n0, acc);

  const int tid = threadIdx.x, lane = tid & 63, w = tid >> 6;
  const int wm = w >> 1, wn = w & 1;
  const int lr = lane & 15, lq = lane >> 4;
#pragma unroll
  for (int i = 0; i < 4; i++) {
#pragma unroll
    for (int j = 0; j < 2; j++) {
      int col   = n0 + wn * 32 + j * 16 + lr;
      int mbase = m0 + wm * 64 + i * 16 + lq * 4;
      float bv_ = bias[col];
      int h = col >> 6, d = col & 63;
      if (mode == 1) {
#pragma unroll
        for (int r = 0; r < 4; r++) {
          int m = mbase + r, b = m >> 11, s = m & (SEQ - 1);
          out[((size_t)(b * HEADS + h) * SEQ + s) * DH + d] = f2bf(acc[i][j][r] + bv_);
        }
      } else {
        int b = mbase >> 11, s = mbase & (SEQ - 1);
        u16x4 pk;
        pk.x = f2bf(acc[i][j][0] + bv_);
        pk.y = f2bf(acc[i][j][1] + bv_);
        pk.z = f2bf(acc[i][j][2] + bv_);
        pk.w = f2bf(acc[i][j][3] + bv_);
        *(u16x4*)&out[((size_t)(b * HEADS + h) * DH + d) * SEQ + s] = pk;
      }
    }
  }
}

// output projection: fp32 out
__global__ __launch_bounds__(256) void gemm_out(const u16* __restrict__ A, const u16* __restrict__ Bt,
                                                const float* __restrict__ bias, float* __restrict__ out) {
  __shared__ __align__(16) u16 As[128 * 64];
  __shared__ __align__(16) u16 Bs[64 * 64];
  const int m0 = blockIdx.y * 128, n0 = blockIdx.x * 64;
  f32x4 acc[4][2];
  gemm_core(A, Bt, As, Bs, m0, n0, acc);

  const int tid = threadIdx.x, lane = tid & 63, w = tid >> 6;
  const int wm = w >> 1, wn = w & 1;
  const int lr = lane & 15, lq = lane >> 4;
#pragma unroll
  for (int i = 0; i < 4; i++) {
#pragma unroll
    for (int j = 0; j < 2; j++) {
      int col   = n0 + wn * 32 + j * 16 + lr;
      int mbase = m0 + wm * 64 + i * 16 + lq * 4;
      float bv_ = bias[col];
#pragma unroll
      for (int r = 0; r < 4; r++)
        out[(size_t)(mbase + r) * EMB + col] = acc[i][j][r] + bv_;
    }
  }
}

// ---------------- fused causal attention, paired q-tiles ----------------
// grid (16, B*H); 512 thr = 8 waves. waves 0-3: q-tile bx, waves 4-7: q-tile 31-bx.
// Shared K/V staging; uniform trip count = 32-bx; register prefetch of next tile.
__global__ __launch_bounds__(512) void attn_fwd(const u16* __restrict__ Q,
                                                const u16* __restrict__ Kg,
                                                const u16* __restrict__ Vt,
                                                u16* __restrict__ O) {
  __shared__ __align__(16) u16 Ks[64 * 80];      // [key][d], stride 80
  __shared__ __align__(16) u16 Vs[64 * 80];      // [d][key]
  __shared__ __align__(16) u16 Ps[8][16 * 80];   // per-wave P tile
  const int tid = threadIdx.x, lane = tid & 63, w = tid >> 6;
  const int lr = lane & 15, lq = lane >> 4;
  const int bh = blockIdx.y, bx = blockIdx.x;
  const int qtA = bx, qtB = 31 - bx;             // qtB >= qtA (bx < 16)
  const int myqt = (w < 4) ? qtA : qtB;
  const int rowoff = (w & 3) * 16;
  const size_t qkbase = (size_t)bh * SEQ * DH;
  const size_t vbase  = (size_t)bh * DH * SEQ;
  const u16* kgp = Kg + qkbase;
  const u16* vtp = Vt + vbase;

  s16x8 qf0, qf1;
  {
    const u16* qrow = Q + qkbase + (size_t)(myqt * 64 + rowoff + lr) * DH;
    qf0 = *(const s16x8*)&qrow[lq * 8];
    qf1 = *(const s16x8*)&qrow[32 + lq * 8];
  }
  f32x4 o[4];
#pragma unroll
  for (int t = 0; t < 4; t++) o[t] = (f32x4){0.f, 0.f, 0.f, 0.f};
  float mrow[4] = {-3e38f, -3e38f, -3e38f, -3e38f};
  float lsum[4] = {0.f, 0.f, 0.f, 0.f};

  // staging assignment: 512 threads, one 16B K-chunk + one 16B V-chunk each
  const int srow = tid >> 3, c8 = (tid & 7) * 8;
  s16x8 kreg = *(const s16x8*)&kgp[(size_t)srow * DH + c8];
  s16x8 vreg = *(const s16x8*)&vtp[(size_t)srow * SEQ + c8];

  const int nkt = qtB + 1;
  for (int kt = 0; kt < nkt; ++kt) {
    __syncthreads();  // previous iteration's readers done
    *(s16x8*)&Ks[srow * 80 + c8] = kreg;
    *(s16x8*)&Vs[srow * 80 + c8] = vreg;
    __syncthreads();
    if (kt + 1 < nkt) {  // prefetch next tile into regs (overlaps compute)
      kreg = *(const s16x8*)&kgp[(size_t)((kt + 1) * 64 + srow) * DH + c8];
      vreg = *(const s16x8*)&vtp[(size_t)srow * SEQ + (kt + 1) * 64 + c8];
    }
    if (kt <= myqt) {  // wave-uniform
      // S = Q @ K^T  (16 x 64 per wave)
      f32x4 sc[4];
#pragma unroll
      for (int t = 0; t < 4; t++) {
        s16x8 kf0 = *(const s16x8*)&Ks[(t * 16 + lr) * 80 + lq * 8];
        s16x8 kf1 = *(const s16x8*)&Ks[(t * 16 + lr) * 80 + 32 + lq * 8];
        f32x4 z = (f32x4){0.f, 0.f, 0.f, 0.f};
        z = __builtin_amdgcn_mfma_f32_16x16x32_bf16(qf0, kf0, z, 0, 0, 0);
        z = __builtin_amdgcn_mfma_f32_16x16x32_bf16(qf1, kf1, z, 0, 0, 0);
        sc[t] = z;
      }
      const bool diag = (kt == myqt);
      float pv[4][4], rmax[4], rsum[4], alpha[4];
#pragma unroll
      for (int r = 0; r < 4; r++) {
        int qrow = rowoff + lq * 4 + r;  // local row in 64-tile
        float mx = -3e38f;
#pragma unroll
        for (int t = 0; t < 4; t++) {
          float s = sc[t][r] * 0.03125f;  // 1/sqrt(1024)
          if (diag && (t * 16 + lr) > qrow) s = -1e9f;
          pv[t][r] = s;
          mx = fmaxf(mx, s);
        }
        rmax[r] = mx;
      }
#pragma unroll
      for (int off = 1; off < 16; off <<= 1)
#pragma unroll
        for (int r = 0; r < 4; r++) rmax[r] = fmaxf(rmax[r], __shfl_xor(rmax[r], off));
#pragma unroll
      for (int r = 0; r < 4; r++) {
        float mnew = fmaxf(mrow[r], rmax[r]);
        alpha[r] = __expf(mrow[r] - mnew);
        mrow[r] = mnew;
        float sum = 0.f;
#pragma unroll
        for (int t = 0; t < 4; t++) {
          float p = __expf(pv[t][r] - mnew);
          pv[t][r] = p;
          sum += p;
        }
        rsum[r] = sum;
      }
#pragma unroll
      for (int off = 1; off < 16; off <<= 1)
#pragma unroll
        for (int r = 0; r < 4; r++) rsum[r] += __shfl_xor(rsum[r], off);
#pragma unroll
      for (int r = 0; r < 4; r++) {
        lsum[r] = lsum[r] * alpha[r] + rsum[r];
#pragma unroll
        for (int t = 0; t < 4; t++) o[t][r] *= alpha[r];
      }

      // P -> LDS (per-wave buffer: no block barrier needed), back as A-operand
      u16* pw = &Ps[w][0];
#pragma unroll
      for (int t = 0; t < 4; t++)
#pragma unroll
        for (int r = 0; r < 4; r++)
          pw[(lq * 4 + r) * 80 + t * 16 + lr] = f2bf(pv[t][r]);

      // O += P @ V
#pragma unroll
      for (int kc = 0; kc < 2; kc++) {
        s16x8 pf = *(const s16x8*)&pw[lr * 80 + kc * 32 + lq * 8];
#pragma unroll
        for (int t = 0; t < 4; t++) {
          s16x8 vf = *(const s16x8*)&Vs[(t * 16 + lr) * 80 + kc * 32 + lq * 8];
          o[t] = __builtin_amdgcn_mfma_f32_16x16x32_bf16(pf, vf, o[t], 0, 0, 0);
        }
      }
    }
  }

  // epilogue: O[m][h*64+d] bf16
  const int b = bh >> 4, h = bh & 15;
#pragma unroll
  for (int t = 0; t < 4; t++) {
#pragma unroll
    for (int r = 0; r < 4; r++) {
      int m = b * SEQ + myqt * 64 + rowoff + lq * 4 + r;
      O[(size_t)m * EMB + h * 64 + t * 16 + lr] = f2bf(o[t][r] / lsum[r]);
    }
  }
}

extern "C" void kernel_launch(void* const* d_in, const int* in_sizes, int n_in,
                              void* d_out, int out_size, void* d_ws, size_t ws_size,
                              hipStream_t stream) {
  const float* x  = (const float*)d_in[0];
  const float* Wq = (const float*)d_in[2];
  const float* bq = (const float*)d_in[3];
  const float* Wk = (const float*)d_in[4];
  const float* bk = (const float*)d_in[5];
  const float* Wv = (const float*)d_in[6];
  const float* bv = (const float*)d_in[7];
  const float* Wo = (const float*)d_in[8];
  const float* bo = (const float*)d_in[9];

  char* ws = (char*)d_ws;
  const size_t MB = 1024 * 1024;
  u16* Qb  = (u16*)(ws + 0 * MB);    // [B][H][S][Dh] bf16
  u16* Kb  = (u16*)(ws + 8 * MB);    // [B][H][S][Dh] bf16
  u16* Vtb = (u16*)(ws + 16 * MB);   // [B][H][Dh][S] bf16
  u16* xb  = (u16*)(ws + 24 * MB);   // [M][E] bf16
  u16* Ob  = xb;                     // alias: xb dead after QKV GEMMs
  u16* Wqt = (u16*)(ws + 32 * MB);
  u16* Wkt = (u16*)(ws + 34 * MB);
  u16* Wvt = (u16*)(ws + 36 * MB);
  u16* Wot = (u16*)(ws + 38 * MB);

  cvt_x_kernel<<<(MTOT * EMB) / (256 * 4), 256, 0, stream>>>(x, xb);
  cvt_wt_kernel<<<dim3(EMB / 32, EMB / 32, 4), dim3(32, 8), 0, stream>>>(
      Wq, Wk, Wv, Wo, Wqt, Wkt, Wvt, Wot);

  gemm_qkv<<<dim3(EMB / 64, MTOT / 128, 3), 256, 0, stream>>>(
      xb, Wqt, Wkt, Wvt, bq, bk, bv, Qb, Kb, Vtb);

  attn_fwd<<<dim3(16, NBATCH * HEADS), 512, 0, stream>>>(Qb, Kb, Vtb, Ob);

  gemm_out<<<dim3(EMB / 64, MTOT / 128), 256, 0, stream>>>(Ob, Wot, bo, (float*)d_out);
}